// Round 15
// baseline (322.235 us; speedup 1.0000x reference)
//
#include <hip/hip_runtime.h>
#include <hip/hip_bf16.h>
#include <math.h>

#define NN 50000
#define NE 800000
#define NREL 4
#define NHEAD 8
#define NSEG (NREL * NN)            // 200000 (rel,dst) segments
#define BCAP 26                     // bucket capacity (Poisson(4) tail ~1e-13)

typedef __hip_bfloat16 bf16;
typedef short short8 __attribute__((ext_vector_type(8)));
typedef float floatx4 __attribute__((ext_vector_type(4)));

#define LOG2E 1.4426950408889634f

__device__ __forceinline__ float b2f(bf16 v) { return __bfloat162float(v); }
__device__ __forceinline__ float us2f(unsigned short u) {
    return __uint_as_float(((unsigned)u) << 16);
}
__device__ __forceinline__ unsigned short f2us(float v) {
    bf16 b = __float2bfloat16(v);
    return *(unsigned short*)&b;
}

// Exact-enough GELU: erf via Abramowitz-Stegun 7.1.26 (|err| <= 1.5e-7).
__device__ __forceinline__ float gelu_f(float v) {
    float z = v * 0.70710678118654752f;
    float az = fabsf(z);
    float t = __builtin_amdgcn_rcpf(__builtin_fmaf(0.3275911f, az, 1.f));
    float p = t * (0.254829592f +
              t * (-0.284496736f +
              t * (1.421413741f +
              t * (-1.453152027f +
              t * 1.061405429f))));
    float ex = __builtin_amdgcn_exp2f(az * az * -LOG2E);
    float er = copysignf(1.f - p * ex, z);
    return 0.5f * v * (1.f + er);
}

// ---------------------------------------------------------------------------
// Diagnostic: fill out with 1000.0 when ws_size is insufficient
// ---------------------------------------------------------------------------
__global__ void fill_kernel(float* __restrict__ out, int n) {
    int t = blockIdx.x * blockDim.x + threadIdx.x;
    if (t < n) out[t] = 1000.0f;
}

// ---------------------------------------------------------------------------
// Pack weights transposed to [outcol][k] bf16, AND zero the bucket counters.
// Wt[768][128]: rows 0..511 W_rel, 512..639 W_self,
//               640..671 es-vectors (log2e * W_r @ a_src), 672..703 ed-vectors
//               (log2e-scaled), 704..767 zero padding.
// Wct[128][128]: W_cross transposed.
// ---------------------------------------------------------------------------
__global__ void prep_kernel(const float* __restrict__ W_rel,
                            const float* __restrict__ W_self,
                            const float* __restrict__ W_cross,
                            const float* __restrict__ a_src,
                            const float* __restrict__ a_dst,
                            bf16* __restrict__ Wt, bf16* __restrict__ Wct,
                            int* __restrict__ counts) {
    int t = blockIdx.x * blockDim.x + threadIdx.x;
    if (t < NSEG) counts[t] = 0;
    if (t < 768 * 128) {
        int row = t >> 7, k = t & 127;
        float v;
        if (row < 512) {
            int r = row >> 7, c = row & 127;
            v = W_rel[(r * 128 + k) * 128 + c];
        } else if (row < 640) {
            v = W_self[k * 128 + (row - 512)];
        } else if (row < 704) {
            int q = row - 640;
            bool is_src = q < 32;
            int qq = is_src ? q : q - 32;
            int r = qq >> 3, h = qq & 7;
            const float* av = (is_src ? a_src : a_dst) + (r * 8 + h) * 16;
            const float* wr = W_rel + (size_t)(r * 128 + k) * 128 + h * 16;
            float s = 0.f;
            #pragma unroll
            for (int dd = 0; dd < 16; ++dd) s += wr[dd] * av[dd];
            v = s * LOG2E;   // prescale so agg uses exp2 directly
        } else {
            v = 0.f;
        }
        Wt[t] = __float2bfloat16(v);
    } else if (t < 768 * 128 + 128 * 128) {
        int u = t - 768 * 128;
        int n = u >> 7, k = u & 127;
        Wct[u] = __float2bfloat16(W_cross[k * 128 + n]);
    }
}

// ---------------------------------------------------------------------------
// Single-pass node GEMM: A staged ONCE (64x128 bf16 in LDS), all 6 col-tiles
// computed per block with B-fragments loaded directly from L2-resident Wt.
// grid = (782, 2): y==0 -> bucket scatter (first, overlaps); y==1 -> GEMM.
// Tiles t: 0..3 -> Xb[rel=t]; 4 -> S f32; 5 -> es/ed bf16.
// Wave w: rows (w&1)*32..+32, cols (w>>1)*64..+64 of each 64x128 tile.
// ---------------------------------------------------------------------------
__global__ __launch_bounds__(256) void gemm_node(
    const float* __restrict__ Ain,
    const bf16* __restrict__ Bt,
    bf16* __restrict__ outb,
    float* __restrict__ outf,
    unsigned short* __restrict__ es_u,
    unsigned short* __restrict__ ed_u,
    const int* __restrict__ ei,
    const int* __restrict__ et,
    int* __restrict__ counts,
    unsigned short* __restrict__ bkt,
    int M)
{
    if (blockIdx.y == 0) {
        int idx = blockIdx.x * 256 + threadIdx.x;
        int stride = gridDim.x * 256;
        for (int e = idx; e < NE; e += stride) {
            int seg = et[e] * NN + ei[NE + e];
            int pos = atomicAdd(&counts[seg], 1);
            if (pos < BCAP) bkt[(unsigned)seg * BCAP + pos] = (unsigned short)ei[e];
        }
        return;
    }

    __shared__ __align__(16) char smem[20480];
    short (*As)[64][40] = (short (*)[64][40])smem;   // [kc][row][k-in-chunk pad40]

    const int tid  = threadIdx.x;
    const int wave = tid >> 6, lane = tid & 63;
    const int quad = lane >> 4, l16 = lane & 15;
    const int wr_ = wave & 1, wc = wave >> 1;        // row-half, col-half
    const int row0 = blockIdx.x * 64;

    // ---- stage A once: thread t covers row t>>2, k-chunk t&3 (coalesced) ----
    {
        int r = tid >> 2, kc = tid & 3;
        int gr = row0 + r;
        const float* ap = Ain + (((size_t)gr) << 7) + kc * 32;
        #pragma unroll
        for (int i = 0; i < 4; ++i) {
            short8 v = {0, 0, 0, 0, 0, 0, 0, 0};
            if (gr < M) {
                float4 f0 = *(const float4*)(ap + i * 8);
                float4 f1 = *(const float4*)(ap + i * 8 + 4);
                v = (short8){(short)f2us(f0.x), (short)f2us(f0.y),
                             (short)f2us(f0.z), (short)f2us(f0.w),
                             (short)f2us(f1.x), (short)f2us(f1.y),
                             (short)f2us(f1.z), (short)f2us(f1.w)};
            }
            *(short8*)&As[kc][r][i * 8] = v;
        }
    }
    __syncthreads();

    // ---- hoist A fragments to registers (8 x short8 = 32 VGPRs) ----
    short8 av[4][2];
    #pragma unroll
    for (int kc = 0; kc < 4; ++kc)
        #pragma unroll
        for (int mt = 0; mt < 2; ++mt)
            av[kc][mt] = *(const short8*)&As[kc][wr_ * 32 + mt * 16 + l16][quad * 8];
    __syncthreads();   // As space is now reused by the wave-private epilogue

    float* ct = (float*)(smem + wave * 4352);        // wave-private [16][68] f32
    const int rr2 = lane >> 2;
    const int cc0 = (lane & 3) * 16;

    #pragma unroll 1
    for (int t = 0; t < 6; ++t) {
        floatx4 acc[2][4];
        #pragma unroll
        for (int i = 0; i < 2; ++i)
            #pragma unroll
            for (int j = 0; j < 4; ++j) acc[i][j] = (floatx4){0.f, 0.f, 0.f, 0.f};

        #pragma unroll
        for (int kc = 0; kc < 4; ++kc) {
            short8 bv[4];
            #pragma unroll
            for (int nt = 0; nt < 4; ++nt)
                bv[nt] = *(const short8*)(Bt +
                    (((size_t)(t * 128 + wc * 64 + nt * 16 + l16)) << 7) + kc * 32 + quad * 8);
            #pragma unroll
            for (int mt = 0; mt < 2; ++mt)
                #pragma unroll
                for (int nt = 0; nt < 4; ++nt)
                    acc[mt][nt] = __builtin_amdgcn_mfma_f32_16x16x32_bf16(
                        av[kc][mt], bv[nt], acc[mt][nt], 0, 0, 0);
        }

        if (t == 5) {
            // es/ed columns (bf16): q = nt*16+l16 in 0..63 for wc==0; wc==1 pad
            if (wc == 0) {
                #pragma unroll
                for (int mt = 0; mt < 2; ++mt) {
                    #pragma unroll
                    for (int reg = 0; reg < 4; ++reg) {
                        int gr = row0 + wr_ * 32 + mt * 16 + quad * 4 + reg;
                        if (gr >= M) continue;
                        #pragma unroll
                        for (int nt = 0; nt < 4; ++nt) {
                            int q = nt * 16 + l16;
                            unsigned short v = f2us(acc[mt][nt][reg]);
                            if (q < 32)
                                es_u[(unsigned)((q >> 3) * NN + gr) * 8u + (unsigned)(q & 7)] = v;
                            else
                                ed_u[(unsigned)(((q - 32) >> 3) * NN + gr) * 8u + (unsigned)((q - 32) & 7)] = v;
                        }
                    }
                }
            }
        } else {
            // LDS-transpose epilogue (wave-private ct; no cross-wave sync)
            for (int mt = 0; mt < 2; ++mt) {
                #pragma unroll
                for (int nt = 0; nt < 4; ++nt)
                    #pragma unroll
                    for (int reg = 0; reg < 4; ++reg)
                        ct[(quad * 4 + reg) * 68 + nt * 16 + l16] = acc[mt][nt][reg];
                __builtin_amdgcn_s_waitcnt(0);  // drain ds_write before ds_read (same wave)

                int gr2 = row0 + wr_ * 32 + mt * 16 + rr2;
                if (gr2 < M) {
                    float4 f0 = *(const float4*)&ct[rr2 * 68 + cc0];
                    float4 f1 = *(const float4*)&ct[rr2 * 68 + cc0 + 4];
                    float4 f2 = *(const float4*)&ct[rr2 * 68 + cc0 + 8];
                    float4 f3 = *(const float4*)&ct[rr2 * 68 + cc0 + 12];
                    int cb = wc * 64 + cc0;
                    if (t == 4) {
                        float* dst = outf + (((size_t)gr2) << 7) + cb;
                        ((float4*)dst)[0] = f0;
                        ((float4*)dst)[1] = f1;
                        ((float4*)dst)[2] = f2;
                        ((float4*)dst)[3] = f3;
                    } else {
                        float tmp[16] = {f0.x, f0.y, f0.z, f0.w, f1.x, f1.y, f1.z, f1.w,
                                         f2.x, f2.y, f2.z, f2.w, f3.x, f3.y, f3.z, f3.w};
                        short8 o0, o1;
                        #pragma unroll
                        for (int j = 0; j < 8; ++j) o0[j] = (short)f2us(tmp[j]);
                        #pragma unroll
                        for (int j = 0; j < 8; ++j) o1[j] = (short)f2us(tmp[8 + j]);
                        bf16* dst = outb + ((size_t)(t * NN + gr2) << 7) + cb;
                        *(short8*)dst = o0;
                        *(short8*)(dst + 8) = o1;
                    }
                }
            }
        }
    }
}

// ---------------------------------------------------------------------------
// Batched aggregation (R13-verified): grid.y = rel, one wave per dst node.
// Output Gb4 NODE-MAJOR (row = n*4+rel); lane 0 writes validity byte.
// ---------------------------------------------------------------------------
__global__ __launch_bounds__(256) void agg_kernel(
    const unsigned short* __restrict__ bkt, const int* __restrict__ counts,
    const bf16* __restrict__ Xb, const unsigned short* __restrict__ es_u,
    const unsigned short* __restrict__ ed_u, const float* __restrict__ bias_rel,
    bf16* __restrict__ Gb4, unsigned char* __restrict__ flag)
{
    const int rel = blockIdx.y;
    const int n = blockIdx.x * 4 + (threadIdx.x >> 6);
    if (n >= NN) return;
    const int l = threadIdx.x & 63;
    const int h = l >> 3;
    const int f = l * 2;
    const unsigned seg = (unsigned)(rel * NN + n);
    int cnt = __builtin_amdgcn_readfirstlane(counts[seg]);
    cnt = cnt < BCAP ? cnt : BCAP;
    const unsigned short* bk = bkt + seg * (unsigned)BCAP;
    const float edv = us2f(ed_u[seg * 8u + (unsigned)h]);
    float a0 = 0.f, a1 = 0.f, den = 0.f;
    const unsigned short* Xr = (const unsigned short*)Xb + (unsigned)rel * (unsigned)(NN * 128);
    const unsigned short* esr = es_u + (unsigned)rel * (unsigned)(NN * 8);

    int e = 0;
    for (; e + 3 < cnt; e += 4) {
        int s0 = __builtin_amdgcn_readfirstlane((int)bk[e]);
        int s1 = __builtin_amdgcn_readfirstlane((int)bk[e + 1]);
        int s2 = __builtin_amdgcn_readfirstlane((int)bk[e + 2]);
        int s3 = __builtin_amdgcn_readfirstlane((int)bk[e + 3]);
        float e0 = us2f(esr[(unsigned)s0 * 8u + (unsigned)h]);
        float e1 = us2f(esr[(unsigned)s1 * 8u + (unsigned)h]);
        float e2 = us2f(esr[(unsigned)s2 * 8u + (unsigned)h]);
        float e3 = us2f(esr[(unsigned)s3 * 8u + (unsigned)h]);
        ushort2 u0 = *(const ushort2*)(Xr + (unsigned)s0 * 128u + (unsigned)f);
        ushort2 u1 = *(const ushort2*)(Xr + (unsigned)s1 * 128u + (unsigned)f);
        ushort2 u2 = *(const ushort2*)(Xr + (unsigned)s2 * 128u + (unsigned)f);
        ushort2 u3 = *(const ushort2*)(Xr + (unsigned)s3 * 128u + (unsigned)f);
        float aa0 = e0 + edv, aa1 = e1 + edv, aa2 = e2 + edv, aa3 = e3 + edv;
        float w0 = __builtin_amdgcn_exp2f(fmaxf(aa0, 0.2f * aa0));
        float w1 = __builtin_amdgcn_exp2f(fmaxf(aa1, 0.2f * aa1));
        float w2 = __builtin_amdgcn_exp2f(fmaxf(aa2, 0.2f * aa2));
        float w3 = __builtin_amdgcn_exp2f(fmaxf(aa3, 0.2f * aa3));
        a0 += w0 * us2f(u0.x) + w1 * us2f(u1.x) + w2 * us2f(u2.x) + w3 * us2f(u3.x);
        a1 += w0 * us2f(u0.y) + w1 * us2f(u1.y) + w2 * us2f(u2.y) + w3 * us2f(u3.y);
        den += (w0 + w1) + (w2 + w3);
    }
    for (; e < cnt; ++e) {
        int s0 = __builtin_amdgcn_readfirstlane((int)bk[e]);
        float e0 = us2f(esr[(unsigned)s0 * 8u + (unsigned)h]);
        ushort2 u0 = *(const ushort2*)(Xr + (unsigned)s0 * 128u + (unsigned)f);
        float aa0 = e0 + edv;
        float w0 = __builtin_amdgcn_exp2f(fmaxf(aa0, 0.2f * aa0));
        a0 += w0 * us2f(u0.x);
        a1 += w0 * us2f(u0.y);
        den += w0;
    }

    float inv = den > 0.f ? __builtin_amdgcn_rcpf(den) : 0.f;
    float2 bv = *(const float2*)(bias_rel + (unsigned)rel * 128u + (unsigned)f);
    float v0 = gelu_f(__builtin_fmaf(a0, inv, bv.x));
    float v1 = gelu_f(__builtin_fmaf(a1, inv, bv.y));
    ushort2 o;
    o.x = f2us(v0);
    o.y = f2us(v1);
    *(ushort2*)((unsigned short*)Gb4 + ((unsigned)n * 4u + (unsigned)rel) * 128u + (unsigned)f) = o;
    if (l == 0) flag[(unsigned)n * 4u + (unsigned)rel] = (unsigned char)(cnt > 0);
}

// ---------------------------------------------------------------------------
// Fused cross-GEMM + lang softmax, 64-row tiles (R14-verified).
// A = Gb4 node-major bf16 [NN*4,128]; reg = rel, quad = node in C-layout.
// Reads S from `out` (d_out) and overwrites the same element per thread.
// ---------------------------------------------------------------------------
__global__ __launch_bounds__(256) void gemm_lang(
    const bf16* __restrict__ A,
    const bf16* __restrict__ Bt,
    const unsigned char* __restrict__ flag,
    const float* __restrict__ asl_g,
    const float* __restrict__ adl_g,
    const float* __restrict__ bias_lang,
    float* __restrict__ out)
{
    __shared__ __align__(16) char smem[15360];
    short (*As)[40] = (short (*)[40])smem;            // 64 x 40
    short (*Bs)[40] = (short (*)[40])(smem + 5120);   // 128 x 40

    const int M = NN * NREL;
    const int tid  = threadIdx.x;
    const int wave = tid >> 6, lane = tid & 63;
    const int quad = lane >> 4, l16 = lane & 15;
    const int wr_ = wave & 1, wc = wave >> 1;
    const int row0 = blockIdx.x * 64;

    floatx4 acc[2][4];
    #pragma unroll
    for (int i = 0; i < 2; ++i)
        #pragma unroll
        for (int j = 0; j < 4; ++j) acc[i][j] = (floatx4){0.f, 0.f, 0.f, 0.f};

    for (int k0 = 0; k0 < 128; k0 += 32) {
        {
            int c = tid;
            int r = c >> 2, off = (c & 3) * 8;
            int gr = row0 + r;
            short8 v = {0, 0, 0, 0, 0, 0, 0, 0};
            if (gr < M)
                v = *(const short8*)(A + (((size_t)gr) << 7) + k0 + off);
            *(short8*)&As[r][off] = v;
        }
        #pragma unroll
        for (int i = 0; i < 2; ++i) {
            int c = tid * 2 + i;
            int r = c >> 2, off = (c & 3) * 8;
            short8 w = *(const short8*)(Bt + (((size_t)r) << 7) + k0 + off);
            *(short8*)&Bs[r][off] = w;
        }
        __syncthreads();

        short8 av[2], bv[4];
        #pragma unroll
        for (int mt = 0; mt < 2; ++mt)
            av[mt] = *(const short8*)&As[wr_ * 32 + mt * 16 + l16][quad * 8];
        #pragma unroll
        for (int nt = 0; nt < 4; ++nt)
            bv[nt] = *(const short8*)&Bs[wc * 64 + nt * 16 + l16][quad * 8];
        #pragma unroll
        for (int mt = 0; mt < 2; ++mt)
            #pragma unroll
            for (int nt = 0; nt < 4; ++nt)
                acc[mt][nt] = __builtin_amdgcn_mfma_f32_16x16x32_bf16(
                    av[mt], bv[nt], acc[mt][nt], 0, 0, 0);
        __syncthreads();
    }

    // fused lang epilogue: rows = node*4+rel -> reg = rel, quad/mt = node
    const int nb0 = blockIdx.x * 16 + wr_ * 8;
    #pragma unroll
    for (int nt = 0; nt < 4; ++nt) {
        int col = wc * 64 + nt * 16 + l16;
        float asl = asl_g[col];
        float adl = adl_g[col];
        float bl  = bias_lang[col];
        #pragma unroll
        for (int mt = 0; mt < 2; ++mt) {
            int node = nb0 + mt * 4 + quad;
            bool ok = node < NN;
            float Sv = ok ? out[(unsigned)node * 128u + (unsigned)col] : 0.f;
            float h0 = acc[mt][nt][0], h1 = acc[mt][nt][1];
            float h2 = acc[mt][nt][2], h3 = acc[mt][nt][3];
            float t0 = h0 * asl, t1 = h1 * asl, t2 = h2 * asl, t3 = h3 * asl;
            float ts = Sv * asl, td = Sv * adl;
            #pragma unroll
            for (int off = 1; off < 16; off <<= 1) {
                t0 += __shfl_xor(t0, off);
                t1 += __shfl_xor(t1, off);
                t2 += __shfl_xor(t2, off);
                t3 += __shfl_xor(t3, off);
                ts += __shfl_xor(ts, off);
                td += __shfl_xor(td, off);
            }
            unsigned fl = ok ? *(const unsigned*)(flag + (unsigned)node * 4u) : 0u;
            float aS = ts + td, a0 = t0 + td, a1 = t1 + td, a2 = t2 + td, a3 = t3 + td;
            float lS = fmaxf(aS, 0.2f * aS);
            float l0 = fmaxf(a0, 0.2f * a0);
            float l1 = fmaxf(a1, 0.2f * a1);
            float l2 = fmaxf(a2, 0.2f * a2);
            float l3 = fmaxf(a3, 0.2f * a3);
            bool v0 = (fl & 0x000000FFu) != 0, v1 = (fl & 0x0000FF00u) != 0;
            bool v2 = (fl & 0x00FF0000u) != 0, v3 = (fl & 0xFF000000u) != 0;
            float m = lS;
            if (v0) m = fmaxf(m, l0);
            if (v1) m = fmaxf(m, l1);
            if (v2) m = fmaxf(m, l2);
            if (v3) m = fmaxf(m, l3);
            float eS = __expf(lS - m);
            float e0 = v0 ? __expf(l0 - m) : 0.f;
            float e1 = v1 ? __expf(l1 - m) : 0.f;
            float e2 = v2 ? __expf(l2 - m) : 0.f;
            float e3 = v3 ? __expf(l3 - m) : 0.f;
            float sum = eS + e0 + e1 + e2 + e3;
            float o = eS * Sv + e0 * h0 + e1 * h1 + e2 * h2 + e3 * h3;
            o = o / sum + bl;
            if (ok) out[(unsigned)node * 128u + (unsigned)col] = o;
        }
    }
}

// ---------------------------------------------------------------------------
extern "C" void kernel_launch(void* const* d_in, const int* in_sizes, int n_in,
                              void* d_out, int out_size, void* d_ws, size_t ws_size,
                              hipStream_t stream) {
    const float* node_inp     = (const float*)d_in[0];
    const int*   edge_index   = (const int*)d_in[1];
    const int*   edge_type    = (const int*)d_in[2];
    const float* W_rel        = (const float*)d_in[3];
    const float* att_src_rel  = (const float*)d_in[4];
    const float* att_dst_rel  = (const float*)d_in[5];
    const float* bias_rel     = (const float*)d_in[6];
    const float* W_self       = (const float*)d_in[7];
    const float* W_cross      = (const float*)d_in[8];
    const float* att_src_lang = (const float*)d_in[9];
    const float* att_dst_lang = (const float*)d_in[10];
    const float* bias_lang    = (const float*)d_in[11];
    (void)in_sizes; (void)n_in;

    // workspace layout (bytes) — total 120,429,376 (<= proven fit)
    const size_t SZ_XB   = (size_t)NREL * NN * 128 * 2;   // 51,200,000 (bf16)
    const size_t SZ_ES   = (size_t)NREL * NN * 8 * 2;     //  3,200,000 (bf16)
    const size_t SZ_GB4  = (size_t)NREL * NN * 128 * 2;   // 51,200,000 (bf16, node-major)
    const size_t SZ_WT   = 768 * 128 * 2;                 //    196,608
    const size_t SZ_WCT  = 128 * 128 * 2;                 //     32,768
    const size_t SZ_BKT  = (size_t)NSEG * BCAP * 2;       // 10,400,000 (uint16 buckets)
    const size_t SZ_CNT  = (size_t)NSEG * 4;              //    800,000
    const size_t SZ_FLG  = (size_t)NN * 4;                //    200,000
    const size_t TOTAL = SZ_XB + 2 * SZ_ES + SZ_GB4 + SZ_WT + SZ_WCT +
                         SZ_BKT + SZ_CNT + SZ_FLG;

    if (ws_size < TOTAL) {
        fill_kernel<<<(out_size + 255) / 256, 256, 0, stream>>>((float*)d_out, out_size);
        return;
    }

    char* ws = (char*)d_ws;
    size_t o = 0;
    bf16*  Xb      = (bf16*)(ws + o);  o += SZ_XB;
    unsigned short* es_u = (unsigned short*)(ws + o); o += SZ_ES;
    unsigned short* ed_u = (unsigned short*)(ws + o); o += SZ_ES;
    bf16*  Gb4     = (bf16*)(ws + o);  o += SZ_GB4;
    bf16*  Wt      = (bf16*)(ws + o);  o += SZ_WT;
    bf16*  Wct     = (bf16*)(ws + o);  o += SZ_WCT;
    unsigned short* bkt = (unsigned short*)(ws + o); o += SZ_BKT;
    int*   counts  = (int*)(ws + o);   o += SZ_CNT;
    unsigned char* flag = (unsigned char*)(ws + o);
    float* S       = (float*)d_out;  // S scratch in d_out; gemm_lang overwrites

    // pack weights (log2e-prescaled att columns) + zero counts
    prep_kernel<<<(NSEG + 255) / 256, 256, 0, stream>>>(
        W_rel, W_self, W_cross, att_src_rel, att_dst_rel, Wt, Wct, counts);

    // fused: bucket scatter (y==0, first) + single-pass GEMM (all 6 tiles)
    dim3 g1((NN + 63) / 64, 2);
    gemm_node<<<g1, 256, 0, stream>>>(node_inp, Wt, Xb, S, es_u, ed_u,
                                      edge_index, edge_type, counts, bkt, NN);

    // batched aggregation (node-major output + flags)
    dim3 ga((NN + 3) / 4, NREL);
    agg_kernel<<<ga, 256, 0, stream>>>(bkt, counts, Xb, es_u, ed_u, bias_rel, Gb4, flag);

    // fused cross-GEMM + lang softmax -> d_out
    dim3 g2((NREL * NN + 63) / 64, 1);
    gemm_lang<<<g2, 256, 0, stream>>>(Gb4, Wct, flag, att_src_lang, att_dst_lang,
                                      bias_lang, (float*)d_out);
}